// Round 13
// baseline (99.384 us; speedup 1.0000x reference)
//
#include <hip/hip_runtime.h>
#include <hip/hip_bf16.h>

typedef __bf16 bf16_t;
typedef bf16_t bf16x4 __attribute__((ext_vector_type(4)));
typedef bf16_t bf16x8 __attribute__((ext_vector_type(8)));
typedef float f32x4 __attribute__((ext_vector_type(4)));

#define AS1 __attribute__((address_space(1)))
#define AS3 __attribute__((address_space(3)))

__device__ __forceinline__ void gload_lds16(const void* g, void* l) {
    __builtin_amdgcn_global_load_lds((const AS1 void*)g, (AS3 void*)l, 16, 0, 0);
}

__device__ __forceinline__ float sigmoidf_(float v) {
    return 1.0f / (1.0f + __expf(-v));
}

// ---------------- fused f32 -> bf16 convert ----------------
__global__ __launch_bounds__(256) void k_convert3(const float* __restrict__ x,
                                                  const float* __restrict__ pr,
                                                  const float* __restrict__ ft,
                                                  bf16_t* __restrict__ dst) {
    const int n4 = 7168 * 256;
    int i = blockIdx.x * 256 + threadIdx.x;
    const int stride = gridDim.x * 256;
    for (; i < n4; i += stride) {
        float4 v;
        if (i < 1048576) v = ((const float4*)x)[i];
        else if (i < 1310720) v = ((const float4*)pr)[i - 1048576];
        else v = ((const float4*)ft)[i - 1310720];
        bf16x4 o;
        o[0] = (bf16_t)v.x; o[1] = (bf16_t)v.y; o[2] = (bf16_t)v.z; o[3] = (bf16_t)v.w;
        ((bf16x4*)dst)[i] = o;
    }
}

// ---------------- fold per-by row-sum partials ----------------
__global__ __launch_bounds__(256) void k_foldrs(const float* __restrict__ rsPart,
                                                float* __restrict__ rsums) {
    const int r = blockIdx.x * 256 + threadIdx.x;
    float s = 0.f;
#pragma unroll
    for (int b = 0; b < 8; ++b) s += rsPart[b * 5120 + r];
    rsums[r] = s;
}

// ---------------- split-K reduce + final epilogue (scrambled partial layout) ------
__global__ __launch_bounds__(256) void k_reduce4(const bf16_t* __restrict__ part,
                                                 const float* __restrict__ rsums,
                                                 const float* __restrict__ pa,
                                                 float* __restrict__ out) {
    const int idx = blockIdx.x * 256 + threadIdx.x;  // [0, 524288)
    const int region = idx >> 13;                    // 64 regions (bx*4+by)
    const int widx = idx & 8191;
    const int wv = widx >> 10;
    const int chunk = (widx >> 6) & 15;
    const int ln = widx & 63;
    const int bx = region >> 2, by = region & 3;
    const int wm = wv >> 2, wn = wv & 3;
    const int fg = chunk >> 1, gp = chunk & 1;
    const int er = (ln >> 4) << 2, ec = ln & 15;
    const long off = (long)idx * 8;

    float sum[8] = {};
#pragma unroll
    for (int s = 0; s < 4; ++s) {
        bf16x8 v = *(const bf16x8*)(part + (long)s * 4194304 + off);
#pragma unroll
        for (int j = 0; j < 8; ++j) sum[j] += (float)v[j];
    }
    const int r0 = bx * 256 + wm * 128 + fg * 16 + er;
    const int c0 = by * 256 + wn * 64 + gp * 32 + ec;
    const float a = pa[0];
#pragma unroll
    for (int q = 0; q < 4; ++q) {
        const float ra = a * rsums[r0 + q];
#pragma unroll
        for (int gh = 0; gh < 2; ++gh) {
            const int c = c0 + gh * 16;
            out[(long)(r0 + q) * 1024 + c] = sum[gh * 4 + q] - ra - rsums[4096 + c];
        }
    }
}

// ================= GEMM2: ring-4 deep-pipelined 256x256 (unchanged R12) ==========
__global__ __launch_bounds__(512, 2) void gemm2_8p(
    const bf16_t* __restrict__ A, const bf16_t* __restrict__ B,
    int NT, long ldab, long ldbb, bf16_t* __restrict__ O1, long zstride) {
    __shared__ char lds[131072];
    const int tid = threadIdx.x;
    const int wave = tid >> 6, lane = tid & 63;
    const int wm = wave >> 2, wn = wave & 3;

    const int gx = gridDim.x, gy = gridDim.y;
    const int o = blockIdx.x + gx * (blockIdx.y + gy * blockIdx.z);
    const int cpx = (gx * gy * (int)gridDim.z) >> 3;
    const int v = (o & 7) * cpx + (o >> 3);
    const int bx = v % gx;
    const int rem = v / gx;
    const int by = rem % gy;
    const int bz = rem / gy;

    const long bm = (long)bx * 256, bn = (long)by * 256;
    const int kb0 = bz * NT * 64;
    const char* Ab = (const char*)A + bm * ldab;
    const char* Bb = (const char*)B + bn * ldbb;

    const int swzcb = ((lane >> 4) << 4) ^ (((lane >> 3) & 1) << 5);
    const int base_a = (wm * 128 + (lane & 15)) * 64 + swzcb;
    const int base_b = (wn * 64 + (lane & 15)) * 64 + swzcb;

    f32x4 acc[8][4] = {};

    auto STAGE = [&](const char* gb, long ld, int kbyte, int ldsoff) {
#pragma unroll
        for (int j = 0; j < 2; ++j) {
            const int oo = (j * 512 + tid) << 4;
            const int r = oo >> 6;
            const int cb = (oo & 63) ^ (((oo >> 9) & 1) << 5);
            gload_lds16(gb + (long)r * ld + kbyte + cb, lds + ldsoff + (oo & ~1023));
        }
    };

#define VM8 asm volatile("s_waitcnt vmcnt(8)" ::: "memory")
#define VM4 asm volatile("s_waitcnt vmcnt(4)" ::: "memory")
#define VM0 asm volatile("s_waitcnt vmcnt(0)" ::: "memory")

    auto PFETCH = [&](int pf) {  // stage slice pf into slot pf&3
        const int kbyte = (kb0 + pf * 32) * 2;
        const int ps = pf & 3;
        STAGE(Ab, ldab, kbyte, ps * 16384);
        STAGE(Bb, ldbb, kbyte, 65536 + ps * 16384);
    };

#define PHASE2(p, WAITSTMT, DOPF)                                               \
    do {                                                                        \
        WAITSTMT;                                                               \
        __builtin_amdgcn_s_barrier();                                           \
        const int slot = (p) & 3;                                               \
        const char* sA = lds + slot * 16384;                                    \
        const char* sB = lds + 65536 + slot * 16384;                            \
        bf16x8 af[8];                                                           \
        bf16x8 bfr[4];                                                          \
        _Pragma("unroll") for (int f = 0; f < 8; ++f)                           \
            af[f] = *(const bf16x8*)(sA + base_a + f * 1024);                   \
        _Pragma("unroll") for (int g = 0; g < 4; ++g)                           \
            bfr[g] = *(const bf16x8*)(sB + base_b + g * 1024);                  \
        if (DOPF) PFETCH((p) + 3);                                              \
        __builtin_amdgcn_sched_barrier(0);                                      \
        __builtin_amdgcn_s_setprio(1);                                          \
        _Pragma("unroll") for (int f = 0; f < 8; ++f)                           \
            _Pragma("unroll") for (int g = 0; g < 4; ++g)                       \
                acc[f][g] = __builtin_amdgcn_mfma_f32_16x16x32_bf16(            \
                    af[f], bfr[g], acc[f][g], 0, 0, 0);                         \
        __builtin_amdgcn_s_setprio(0);                                          \
        __builtin_amdgcn_sched_barrier(0);                                      \
    } while (0)

    const int NP = NT * 2;
    PFETCH(0);
    PFETCH(1);
    PFETCH(2);

    for (int p = 0; p < NP - 3; ++p) PHASE2(p, VM8, 1);
    PHASE2(NP - 3, VM8, 0);
    PHASE2(NP - 2, VM4, 0);
    PHASE2(NP - 1, VM0, 0);

#undef PHASE2
#undef VM8
#undef VM4
#undef VM0

    // scrambled-coalesced partial write
    bf16_t* Op = O1 + (long)bz * zstride + (long)(bx * 4 + by) * 65536 +
                 wave * 8192 + lane * 8;
#pragma unroll
    for (int fg = 0; fg < 8; ++fg)
#pragma unroll
        for (int gp = 0; gp < 2; ++gp) {
            bf16x8 w;
#pragma unroll
            for (int gh = 0; gh < 2; ++gh)
#pragma unroll
                for (int q = 0; q < 4; ++q)
                    w[gh * 4 + q] = (bf16_t)acc[fg][gp * 2 + gh][q];
            *(bf16x8*)(Op + (fg * 2 + gp) * 512) = w;
        }
}

// ================= GEMM1: ring-4 256x256, grid 20x8 = 160 blocks =================
// Traffic: A 10.5MB x8 + B 4MB x20 = 164MB (vs 218 at BM=160). Same per-phase
// instruction mix as gemm2 (4 gload/thread/phase, 12 ds_read, 32 MFMA swapped-op).
// isX = (bx < 16) block-uniform (boundary 4096 = 16*256).
__global__ __launch_bounds__(512, 2) void gemm1_256(
    const bf16_t* __restrict__ A, const bf16_t* __restrict__ B,
    bf16_t* __restrict__ O1, bf16_t* __restrict__ O1b,
    float* __restrict__ rsPart,
    const float* __restrict__ pa, const float* __restrict__ pb,
    const float* __restrict__ pt) {
    __shared__ char lds[131072];
    const int tid = threadIdx.x;
    const int wave = tid >> 6, lane = tid & 63;
    const int wm = wave >> 2, wn = wave & 3;
    const int NT = 16;

    const int gx = gridDim.x, gy = gridDim.y;
    const int o = blockIdx.x + gx * blockIdx.y;
    const int cpx = (gx * gy) >> 3;
    const int v = (o & 7) * cpx + (o >> 3);
    const int bx = v % gx;
    const int by = v / gx;

    const long bm = (long)bx * 256, bn = (long)by * 256;
    const char* Ab = (const char*)A + bm * 2048;
    const char* Bb = (const char*)B + bn * 2048;

    const int swzcb = ((lane >> 4) << 4) ^ (((lane >> 3) & 1) << 5);
    const int base_a = (wm * 128 + (lane & 15)) * 64 + swzcb;
    const int base_b = (wn * 64 + (lane & 15)) * 64 + swzcb;

    f32x4 acc[8][4] = {};

    auto STAGE = [&](const char* gb, int kbyte, int ldsoff) {
#pragma unroll
        for (int j = 0; j < 2; ++j) {
            const int oo = (j * 512 + tid) << 4;
            const int r = oo >> 6;
            const int cb = (oo & 63) ^ (((oo >> 9) & 1) << 5);
            gload_lds16(gb + (long)r * 2048 + kbyte + cb, lds + ldsoff + (oo & ~1023));
        }
    };

#define VM8 asm volatile("s_waitcnt vmcnt(8)" ::: "memory")
#define VM4 asm volatile("s_waitcnt vmcnt(4)" ::: "memory")
#define VM0 asm volatile("s_waitcnt vmcnt(0)" ::: "memory")

    auto PFETCH = [&](int pf) {
        const int kbyte = pf * 64;
        const int ps = pf & 3;
        STAGE(Ab, kbyte, ps * 16384);
        STAGE(Bb, kbyte, 65536 + ps * 16384);
    };

#define PHASE1(p, WAITSTMT, DOPF)                                               \
    do {                                                                        \
        WAITSTMT;                                                               \
        __builtin_amdgcn_s_barrier();                                           \
        const int slot = (p) & 3;                                               \
        const char* sA = lds + slot * 16384;                                    \
        const char* sB = lds + 65536 + slot * 16384;                            \
        bf16x8 af[8];                                                           \
        bf16x8 bfr[4];                                                          \
        _Pragma("unroll") for (int f = 0; f < 8; ++f)                           \
            af[f] = *(const bf16x8*)(sA + base_a + f * 1024);                   \
        _Pragma("unroll") for (int g = 0; g < 4; ++g)                           \
            bfr[g] = *(const bf16x8*)(sB + base_b + g * 1024);                  \
        if (DOPF) PFETCH((p) + 3);                                              \
        __builtin_amdgcn_sched_barrier(0);                                      \
        __builtin_amdgcn_s_setprio(1);                                          \
        _Pragma("unroll") for (int f = 0; f < 8; ++f)                           \
            _Pragma("unroll") for (int g = 0; g < 4; ++g)                       \
                acc[f][g] = __builtin_amdgcn_mfma_f32_16x16x32_bf16(            \
                    bfr[g], af[f], acc[f][g], 0, 0, 0);                         \
        __builtin_amdgcn_s_setprio(0);                                          \
        __builtin_amdgcn_sched_barrier(0);                                      \
    } while (0)

    const int NP = NT * 2;
    PFETCH(0);
    PFETCH(1);
    PFETCH(2);

    for (int p = 0; p < NP - 3; ++p) PHASE1(p, VM8, 1);
    PHASE1(NP - 3, VM8, 0);
    PHASE1(NP - 2, VM4, 0);
    PHASE1(NP - 1, VM0, 0);

#undef PHASE1
#undef VM8
#undef VM4
#undef VM0

    // epilogue scratch reuses ring LDS -> sync all waves first
    __syncthreads();

    // Epilogue: swapped operands -> row m = mf*16+(lane&15), col = g*16+(lane>>4)*4+q
    // Per-frag LDS transpose (col-field XOR, verified R9) -> coalesced 16B stores.
    const bool isX = (bx < 16);  // block-uniform
    const float va = pa[0], vb = pb[0], vt = pt[0];
    bf16_t* gb = isX ? O1 : O1b;
    const long rowoff = isX ? bm : bm - 4096;
    const int lm = lane & 15;
    const int ln4 = (lane >> 4) << 2;
    char* wlds = lds + 4096 + wave * 4096;   // per-wave [16][64] x 2 planes
    const int wswz = (lm & 7) << 4;
    float rs[8];
#pragma unroll
    for (int f = 0; f < 8; ++f) rs[f] = 0.f;

#pragma unroll
    for (int mf = 0; mf < 8; ++mf) {
        const long rbase0 = rowoff + wm * 128 + mf * 16;
#pragma unroll
        for (int g = 0; g < 4; ++g) {
            bf16x4 w0, w1;
#pragma unroll
            for (int q = 0; q < 4; ++q) {
                const float vv = acc[mf][g][q];
                const float s = sigmoidf_(vv);
                const float prod = vv * s;
                w0[q] = (bf16_t)(isX ? prod : (vt * prod + va * s));
                w1[q] = (bf16_t)(isX ? s : (vb * prod));
                rs[mf] += isX ? prod : vb * prod;
            }
            const int a = lm * 128 + ((g * 32 + ln4 * 2) ^ wswz);
            *(bf16x4*)(wlds + a) = w0;
            *(bf16x4*)(wlds + 2048 + a) = w1;
        }
#pragma unroll
        for (int rd = 0; rd < 2; ++rd) {
            const int row = rd * 8 + (lane >> 3);
            const int a = row * 128 + (((lane & 7) * 16) ^ ((row & 7) << 4));
            bf16x8 v0 = *(const bf16x8*)(wlds + a);
            bf16x8 v1 = *(const bf16x8*)(wlds + 2048 + a);
            bf16_t* dst = gb + (rbase0 + row) * 4096 + bn + wn * 64 + (lane & 7) * 8;
            *(bf16x8*)dst = v0;
            *(bf16x8*)(dst + 2048) = v1;
        }
    }

    // rowsums: fold lane>>4 groups, stage in LDS[0,4KB), cross-wave reduce,
    // one non-atomic write per row into per-by slab.
    float* lds_f = (float*)lds;
#pragma unroll
    for (int f = 0; f < 8; ++f) {
        float t = rs[f];
        t += __shfl_xor(t, 16);
        t += __shfl_xor(t, 32);
        if ((lane >> 4) == 0) lds_f[wn * 256 + wm * 128 + f * 16 + lm] = t;
    }
    __syncthreads();
    if (tid < 256) {
        const float s = lds_f[tid] + lds_f[256 + tid] + lds_f[512 + tid] + lds_f[768 + tid];
        rsPart[(long)by * 5120 + bm + tid] = s;
    }
}

extern "C" void kernel_launch(void* const* d_in, const int* in_sizes, int n_in,
                              void* d_out, int out_size, void* d_ws, size_t ws_size,
                              hipStream_t stream) {
    const float* x = (const float*)d_in[0];       // [4096,1024]
    const float* feats = (const float*)d_in[1];   // [2048,1024]
    const float* protos = (const float*)d_in[2];  // [1024,1024]
    const float* pa = (const float*)d_in[3];
    const float* pb = (const float*)d_in[4];
    const float* pt = (const float*)d_in[5];
    float* out = (float*)d_out;                   // [4096,1024]

    constexpr long Bsz = 4096, D = 1024, F = 2048, P = 1024;

    bf16_t* XP = (bf16_t*)d_ws;                   // [5120 x 1024] = [x ; protos]
    bf16_t* F16 = XP + (Bsz + P) * D;             // [2048 x 1024]
    bf16_t* A2 = F16 + F * D;                     // [4096 x 4096] = [ax | sx]
    bf16_t* B2 = A2 + Bsz * 2 * F;                // [1024 x 4096] = [t*bp+a*sp | b*bp]
    float* rsums = (float*)(B2 + P * 2 * F);      // [5120] f32 (folded)
    bf16_t* part = (bf16_t*)(rsums + Bsz + P);    // 4 x [4096*1024] bf16 (scrambled)
    float* rsPart = (float*)(part + 4L * Bsz * P);  // [8][5120] f32 slabs

    k_convert3<<<2048, 256, 0, stream>>>(x, protos, feats, XP);

    // fused GEMM1: [x;protos] @ feats^T  [5120 x 2048], K=1024, 160 blocks
    gemm1_256<<<dim3(20, 8), 512, 0, stream>>>(XP, F16, A2, B2, rsPart, pa, pb, pt);

    // fold 8 per-by row-sum slabs -> rsums[5120]
    k_foldrs<<<20, 256, 0, stream>>>(rsPart, rsums);

    // GEMM2 split-K=4: part[z] = A2 @ B2^T over K-slice z (scrambled layout)
    gemm2_8p<<<dim3(Bsz / 256, P / 256, 4), 512, 0, stream>>>(
        A2, B2, (int)(2 * F / 64 / 4), 2 * F * 2, 2 * F * 2, part, (long)Bsz * P);

    k_reduce4<<<2048, 256, 0, stream>>>(part, rsums, pa, out);
}

// Round 14
// 89.804 us; speedup vs baseline: 1.1067x; 1.1067x over previous
//
#include <hip/hip_runtime.h>
#include <hip/hip_bf16.h>

typedef __bf16 bf16_t;
typedef bf16_t bf16x4 __attribute__((ext_vector_type(4)));
typedef bf16_t bf16x8 __attribute__((ext_vector_type(8)));
typedef float f32x4 __attribute__((ext_vector_type(4)));

#define AS1 __attribute__((address_space(1)))
#define AS3 __attribute__((address_space(3)))

__device__ __forceinline__ void gload_lds16(const void* g, void* l) {
    __builtin_amdgcn_global_load_lds((const AS1 void*)g, (AS3 void*)l, 16, 0, 0);
}
__device__ __forceinline__ void gload_lds4(const void* g, void* l) {
    __builtin_amdgcn_global_load_lds((const AS1 void*)g, (AS3 void*)l, 4, 0, 0);
}

__device__ __forceinline__ float sigmoidf_(float v) {
    return 1.0f / (1.0f + __expf(-v));
}

// ---------------- fused f32 -> bf16 convert ----------------
__global__ __launch_bounds__(256) void k_convert3(const float* __restrict__ x,
                                                  const float* __restrict__ pr,
                                                  const float* __restrict__ ft,
                                                  bf16_t* __restrict__ dst) {
    const int n4 = 7168 * 256;
    int i = blockIdx.x * 256 + threadIdx.x;
    const int stride = gridDim.x * 256;
    for (; i < n4; i += stride) {
        float4 v;
        if (i < 1048576) v = ((const float4*)x)[i];
        else if (i < 1310720) v = ((const float4*)pr)[i - 1048576];
        else v = ((const float4*)ft)[i - 1310720];
        bf16x4 o;
        o[0] = (bf16_t)v.x; o[1] = (bf16_t)v.y; o[2] = (bf16_t)v.z; o[3] = (bf16_t)v.w;
        ((bf16x4*)dst)[i] = o;
    }
}

// ---------------- fold per-by row-sum partials ----------------
__global__ __launch_bounds__(256) void k_foldrs(const float* __restrict__ rsPart,
                                                float* __restrict__ rsums) {
    const int r = blockIdx.x * 256 + threadIdx.x;
    float s = 0.f;
#pragma unroll
    for (int b = 0; b < 8; ++b) s += rsPart[b * 5120 + r];
    rsums[r] = s;
}

// ---------------- split-K reduce + final epilogue (scrambled partial layout) ------
__global__ __launch_bounds__(256) void k_reduce4(const bf16_t* __restrict__ part,
                                                 const float* __restrict__ rsums,
                                                 const float* __restrict__ pa,
                                                 float* __restrict__ out) {
    const int idx = blockIdx.x * 256 + threadIdx.x;  // [0, 524288)
    const int region = idx >> 13;                    // 64 regions (bx*4+by)
    const int widx = idx & 8191;
    const int wv = widx >> 10;
    const int chunk = (widx >> 6) & 15;
    const int ln = widx & 63;
    const int bx = region >> 2, by = region & 3;
    const int wm = wv >> 2, wn = wv & 3;
    const int fg = chunk >> 1, gp = chunk & 1;
    const int er = (ln >> 4) << 2, ec = ln & 15;
    const long off = (long)idx * 8;

    float sum[8] = {};
#pragma unroll
    for (int s = 0; s < 4; ++s) {
        bf16x8 v = *(const bf16x8*)(part + (long)s * 4194304 + off);
#pragma unroll
        for (int j = 0; j < 8; ++j) sum[j] += (float)v[j];
    }
    const int r0 = bx * 256 + wm * 128 + fg * 16 + er;
    const int c0 = by * 256 + wn * 64 + gp * 32 + ec;
    const float a = pa[0];
#pragma unroll
    for (int q = 0; q < 4; ++q) {
        const float ra = a * rsums[r0 + q];
#pragma unroll
        for (int gh = 0; gh < 2; ++gh) {
            const int c = c0 + gh * 16;
            out[(long)(r0 + q) * 1024 + c] = sum[gh * 4 + q] - ra - rsums[4096 + c];
        }
    }
}

// ================= GEMM2: ring-4 deep-pipelined 256x256, KB32 operands ==========
// A2s[kb][4096][32], B2s[kb][1024][32] bf16, kb in [0,128) over virtual K=4096.
// Each K-slice (kb) of a block's panels is a CONTIGUOUS 16KB block -> linear
// gload_lds16 staging (source pre-swizzled within 64B rows, LDS linear, swizzled
// ds_read -- same involution as all prior rounds). Ring-4, VM8 steady state.
__global__ __launch_bounds__(512, 2) void gemm2_8p(
    const bf16_t* __restrict__ A2s, const bf16_t* __restrict__ B2s,
    bf16_t* __restrict__ O1, long zstride) {
    __shared__ char lds[131072];
    const int tid = threadIdx.x;
    const int wave = tid >> 6, lane = tid & 63;
    const int wm = wave >> 2, wn = wave & 3;

    const int gx = gridDim.x, gy = gridDim.y;
    const int o = blockIdx.x + gx * (blockIdx.y + gy * blockIdx.z);
    const int cpx = (gx * gy * (int)gridDim.z) >> 3;
    const int v = (o & 7) * cpx + (o >> 3);
    const int bx = v % gx;
    const int rem = v / gx;
    const int by = rem % gy;
    const int bz = rem / gy;

    const long bm = (long)bx * 256, bn = (long)by * 256;
    const int kb32_0 = bz * 32;  // 32 kb-slices per z
    const char* Ab = (const char*)A2s;
    const char* Bb = (const char*)B2s;

    const int swzcb = ((lane >> 4) << 4) ^ (((lane >> 3) & 1) << 5);
    const int base_a = (wm * 128 + (lane & 15)) * 64 + swzcb;
    const int base_b = (wn * 64 + (lane & 15)) * 64 + swzcb;

    f32x4 acc[8][4] = {};

    // contiguous 16KB slice stage: 2 x 16B per thread
    auto STAGEC = [&](const char* gbase, int ldsoff) {
#pragma unroll
        for (int j = 0; j < 2; ++j) {
            const int oo = (j * 512 + tid) << 4;
            const int cb = (oo & 63) ^ (((oo >> 9) & 1) << 5);
            gload_lds16(gbase + (oo & ~63) + cb, lds + ldsoff + (oo & ~1023));
        }
    };

#define VM8 asm volatile("s_waitcnt vmcnt(8)" ::: "memory")
#define VM4 asm volatile("s_waitcnt vmcnt(4)" ::: "memory")
#define VM0 asm volatile("s_waitcnt vmcnt(0)" ::: "memory")

    auto PFETCH = [&](int pf) {  // stage slice kb32_0+pf into slot pf&3
        const long kb = kb32_0 + pf;
        const int ps = pf & 3;
        STAGEC(Ab + (kb * 4096 + bm) * 64, ps * 16384);
        STAGEC(Bb + (kb * 1024 + bn) * 64, 65536 + ps * 16384);
    };

#define PHASE2(p, WAITSTMT, DOPF)                                               \
    do {                                                                        \
        WAITSTMT;                                                               \
        __builtin_amdgcn_s_barrier();                                           \
        const int slot = (p) & 3;                                               \
        const char* sA = lds + slot * 16384;                                    \
        const char* sB = lds + 65536 + slot * 16384;                            \
        bf16x8 af[8];                                                           \
        bf16x8 bfr[4];                                                          \
        _Pragma("unroll") for (int f = 0; f < 8; ++f)                           \
            af[f] = *(const bf16x8*)(sA + base_a + f * 1024);                   \
        _Pragma("unroll") for (int g = 0; g < 4; ++g)                           \
            bfr[g] = *(const bf16x8*)(sB + base_b + g * 1024);                  \
        if (DOPF) PFETCH((p) + 3);                                              \
        __builtin_amdgcn_sched_barrier(0);                                      \
        __builtin_amdgcn_s_setprio(1);                                          \
        _Pragma("unroll") for (int f = 0; f < 8; ++f)                           \
            _Pragma("unroll") for (int g = 0; g < 4; ++g)                       \
                acc[f][g] = __builtin_amdgcn_mfma_f32_16x16x32_bf16(            \
                    af[f], bfr[g], acc[f][g], 0, 0, 0);                         \
        __builtin_amdgcn_s_setprio(0);                                          \
        __builtin_amdgcn_sched_barrier(0);                                      \
    } while (0)

    const int NP = 32;
    PFETCH(0);
    PFETCH(1);
    PFETCH(2);

    for (int p = 0; p < NP - 3; ++p) PHASE2(p, VM8, 1);
    PHASE2(NP - 3, VM8, 0);
    PHASE2(NP - 2, VM4, 0);
    PHASE2(NP - 1, VM0, 0);

#undef PHASE2
#undef VM8
#undef VM4
#undef VM0

    // scrambled-coalesced partial write
    bf16_t* Op = O1 + (long)bz * zstride + (long)(bx * 4 + by) * 65536 +
                 wave * 8192 + lane * 8;
#pragma unroll
    for (int fg = 0; fg < 8; ++fg)
#pragma unroll
        for (int gp = 0; gp < 2; ++gp) {
            bf16x8 w;
#pragma unroll
            for (int gh = 0; gh < 2; ++gh)
#pragma unroll
                for (int q = 0; q < 4; ++q)
                    w[gh * 4 + q] = (bf16_t)acc[fg][gp * 2 + gh][q];
            *(bf16x8*)(Op + (fg * 2 + gp) * 512) = w;
        }
}

// ================= GEMM1: ring-4 160x256, grid 32x8 = 256 blocks (R12 loop) ======
// Epilogue rewritten for KB32 output layout: direct bf16x4 stores, no LDS
// transpose, no bank conflicts. Swapped-op: row m = mf*16+(lane&15),
// col f = bn + wn*64 + (g>>1)*32 + (g&1)*16 + ln4 + q.
__global__ __launch_bounds__(512, 2) void gemm1_160(
    const bf16_t* __restrict__ A, const bf16_t* __restrict__ B,
    bf16_t* __restrict__ A2s, bf16_t* __restrict__ B2s,
    float* __restrict__ rsPart,
    const float* __restrict__ pa, const float* __restrict__ pb,
    const float* __restrict__ pt) {
    __shared__ char lds[106496];
    const int tid = threadIdx.x;
    const int wave = tid >> 6, lane = tid & 63;
    const int wm = wave >> 2, wn = wave & 3;
    const int NT = 16;

    const int gx = gridDim.x, gy = gridDim.y;
    const int o = blockIdx.x + gx * blockIdx.y;
    const int cpx = (gx * gy) >> 3;
    const int v = (o & 7) * cpx + (o >> 3);
    const int bx = v % gx;
    const int by = v / gx;

    const long bm = (long)bx * 160, bn = (long)by * 256;
    const char* Ab = (const char*)A + bm * 2048;
    const char* Bb = (const char*)B + bn * 2048;

    const int swzcb = ((lane >> 4) << 4) ^ (((lane >> 3) & 1) << 5);
    const int base_a = (wm * 80 + (lane & 15)) * 64 + swzcb;
    const int base_b = (wn * 64 + (lane & 15)) * 64 + swzcb;

    f32x4 acc[5][4] = {};

    auto STAGE_A = [&](int kbyte, int ldsoff) {
        {
            const int oo = tid << 4;
            const int r = oo >> 6;
            const int cb = (oo & 63) ^ (((oo >> 9) & 1) << 5);
            gload_lds16(Ab + (long)r * 2048 + kbyte + cb, lds + ldsoff + (oo & ~1023));
        }
        {
            const int oo = 8192 + (tid << 2);
            const int r = oo >> 6;
            const int cb = (oo & 63) ^ (((oo >> 9) & 1) << 5);
            gload_lds4(Ab + (long)r * 2048 + kbyte + cb, lds + ldsoff + 8192 + wave * 256);
        }
    };
    auto STAGE_B = [&](int kbyte, int ldsoff) {
#pragma unroll
        for (int j = 0; j < 2; ++j) {
            const int oo = (j * 512 + tid) << 4;
            const int r = oo >> 6;
            const int cb = (oo & 63) ^ (((oo >> 9) & 1) << 5);
            gload_lds16(Bb + (long)r * 2048 + kbyte + cb, lds + ldsoff + (oo & ~1023));
        }
    };

#define VM8 asm volatile("s_waitcnt vmcnt(8)" ::: "memory")
#define VM4 asm volatile("s_waitcnt vmcnt(4)" ::: "memory")
#define VM0 asm volatile("s_waitcnt vmcnt(0)" ::: "memory")

    auto PFETCH = [&](int pf) {
        const int kbyte = pf * 64;
        const int ps = pf & 3;
        STAGE_A(kbyte, ps * 10240);
        STAGE_B(kbyte, 40960 + ps * 16384);
    };

#define PHASE1(p, WAITSTMT, DOPF)                                               \
    do {                                                                        \
        WAITSTMT;                                                               \
        __builtin_amdgcn_s_barrier();                                           \
        const int slot = (p) & 3;                                               \
        const char* sA = lds + slot * 10240;                                    \
        const char* sB = lds + 40960 + slot * 16384;                            \
        bf16x8 af[5];                                                           \
        bf16x8 bfr[4];                                                          \
        _Pragma("unroll") for (int f = 0; f < 5; ++f)                           \
            af[f] = *(const bf16x8*)(sA + base_a + f * 1024);                   \
        _Pragma("unroll") for (int g = 0; g < 4; ++g)                           \
            bfr[g] = *(const bf16x8*)(sB + base_b + g * 1024);                  \
        if (DOPF) PFETCH((p) + 3);                                              \
        __builtin_amdgcn_sched_barrier(0);                                      \
        __builtin_amdgcn_s_setprio(1);                                          \
        _Pragma("unroll") for (int f = 0; f < 5; ++f)                           \
            _Pragma("unroll") for (int g = 0; g < 4; ++g)                       \
                acc[f][g] = __builtin_amdgcn_mfma_f32_16x16x32_bf16(            \
                    bfr[g], af[f], acc[f][g], 0, 0, 0);                         \
        __builtin_amdgcn_s_setprio(0);                                          \
        __builtin_amdgcn_sched_barrier(0);                                      \
    } while (0)

    const int NP = NT * 2;
    PFETCH(0);
    PFETCH(1);
    PFETCH(2);

    for (int p = 0; p < NP - 3; ++p) PHASE1(p, VM8, 1);
    PHASE1(NP - 3, VM8, 0);
    PHASE1(NP - 2, VM4, 0);
    PHASE1(NP - 1, VM0, 0);

#undef PHASE1
#undef VM8
#undef VM4
#undef VM0

    // Epilogue: direct KB32 stores. col f = bn + wn*64 + (g>>1)*32 + (g&1)*16+ln4+q
    const float va = pa[0], vb = pb[0], vt = pt[0];
    const int lm = lane & 15;
    const int ln4 = (lane >> 4) << 2;
    const int kbbase = (int)(bn >> 5) + wn * 2;
    float rs[5];
#pragma unroll
    for (int f = 0; f < 5; ++f) rs[f] = 0.f;

#pragma unroll
    for (int mf = 0; mf < 5; ++mf) {
        const long grow = bm + wm * 80 + mf * 16 + lm;  // global output row
        const bool isXf = (grow < 4096);                // frag-aligned boundary
        const long rowidx = isXf ? grow : (grow - 4096);
        const long rowsz = isXf ? 4096 : 1024;
        bf16_t* base = isXf ? A2s : B2s;
#pragma unroll
        for (int g = 0; g < 4; ++g) {
            bf16x4 w0, w1;
            float rsl = 0.f;
#pragma unroll
            for (int q = 0; q < 4; ++q) {
                const float vv = acc[mf][g][q];
                const float s = sigmoidf_(vv);
                const float prod = vv * s;
                w0[q] = (bf16_t)(isXf ? prod : (vt * prod + va * s));
                w1[q] = (bf16_t)(isXf ? s : (vb * prod));
                rsl += isXf ? prod : vb * prod;
            }
            rs[mf] += rsl;
            const long kb = kbbase + (g >> 1);
            const int c0 = (g & 1) * 16 + ln4;
            *(bf16x4*)(base + (kb * rowsz + rowidx) * 32 + c0) = w0;
            *(bf16x4*)(base + ((kb + 64) * rowsz + rowidx) * 32 + c0) = w1;
        }
    }

    // rowsums: fold lane>>4 groups, stage in LDS[0,2560), cross-wave reduce.
    __syncthreads();  // ring slot 0 reads all complete (post-loop), reuse as scratch
    float* lds_f = (float*)lds;
#pragma unroll
    for (int f = 0; f < 5; ++f) {
        float t = rs[f];
        t += __shfl_xor(t, 16);
        t += __shfl_xor(t, 32);
        if ((lane >> 4) == 0) lds_f[wn * 160 + wm * 80 + f * 16 + lm] = t;
    }
    __syncthreads();
    if (tid < 160) {
        const float s = lds_f[tid] + lds_f[160 + tid] + lds_f[320 + tid] + lds_f[480 + tid];
        rsPart[(long)by * 5120 + bm + tid] = s;
    }
}

extern "C" void kernel_launch(void* const* d_in, const int* in_sizes, int n_in,
                              void* d_out, int out_size, void* d_ws, size_t ws_size,
                              hipStream_t stream) {
    const float* x = (const float*)d_in[0];       // [4096,1024]
    const float* feats = (const float*)d_in[1];   // [2048,1024]
    const float* protos = (const float*)d_in[2];  // [1024,1024]
    const float* pa = (const float*)d_in[3];
    const float* pb = (const float*)d_in[4];
    const float* pt = (const float*)d_in[5];
    float* out = (float*)d_out;                   // [4096,1024]

    constexpr long Bsz = 4096, D = 1024, F = 2048, P = 1024;

    bf16_t* XP = (bf16_t*)d_ws;                   // [5120 x 1024] = [x ; protos]
    bf16_t* F16 = XP + (Bsz + P) * D;             // [2048 x 1024]
    bf16_t* A2s = F16 + F * D;                    // KB32: [128][4096][32], 32 MB
    bf16_t* B2s = A2s + Bsz * 2 * F;              // KB32: [128][1024][32], 8 MB
    float* rsums = (float*)(B2s + P * 2 * F);     // [5120] f32 (folded)
    bf16_t* part = (bf16_t*)(rsums + Bsz + P);    // 4 x [4096*1024] bf16 (scrambled)
    float* rsPart = (float*)(part + 4L * Bsz * P);  // [8][5120] f32 slabs

    k_convert3<<<2048, 256, 0, stream>>>(x, protos, feats, XP);

    // fused GEMM1: [x;protos] @ feats^T  [5120 x 2048], K=1024, 256 blocks
    gemm1_160<<<dim3(32, 8), 512, 0, stream>>>(XP, F16, A2s, B2s, rsPart, pa, pb, pt);

    // fold 8 per-by row-sum slabs -> rsums[5120]
    k_foldrs<<<20, 256, 0, stream>>>(rsPart, rsums);

    // GEMM2 split-K=4 over kb slices (scrambled partial layout)
    gemm2_8p<<<dim3(Bsz / 256, P / 256, 4), 512, 0, stream>>>(
        A2s, B2s, part, (long)Bsz * P);

    k_reduce4<<<2048, 256, 0, stream>>>(part, rsums, pa, out);
}

// Round 15
// 88.623 us; speedup vs baseline: 1.1214x; 1.0133x over previous
//
#include <hip/hip_runtime.h>
#include <hip/hip_bf16.h>

typedef __bf16 bf16_t;
typedef bf16_t bf16x4 __attribute__((ext_vector_type(4)));
typedef bf16_t bf16x8 __attribute__((ext_vector_type(8)));
typedef float f32x4 __attribute__((ext_vector_type(4)));

#define AS1 __attribute__((address_space(1)))
#define AS3 __attribute__((address_space(3)))

__device__ __forceinline__ void gload_lds16(const void* g, void* l) {
    __builtin_amdgcn_global_load_lds((const AS1 void*)g, (AS3 void*)l, 16, 0, 0);
}
__device__ __forceinline__ void gload_lds4(const void* g, void* l) {
    __builtin_amdgcn_global_load_lds((const AS1 void*)g, (AS3 void*)l, 4, 0, 0);
}

__device__ __forceinline__ float sigmoidf_(float v) {
    return 1.0f / (1.0f + __expf(-v));
}

// ---------------- fused f32 -> bf16 convert ----------------
__global__ __launch_bounds__(256) void k_convert3(const float* __restrict__ x,
                                                  const float* __restrict__ pr,
                                                  const float* __restrict__ ft,
                                                  bf16_t* __restrict__ dst) {
    const int n4 = 7168 * 256;
    int i = blockIdx.x * 256 + threadIdx.x;
    const int stride = gridDim.x * 256;
    for (; i < n4; i += stride) {
        float4 v;
        if (i < 1048576) v = ((const float4*)x)[i];
        else if (i < 1310720) v = ((const float4*)pr)[i - 1048576];
        else v = ((const float4*)ft)[i - 1310720];
        bf16x4 o;
        o[0] = (bf16_t)v.x; o[1] = (bf16_t)v.y; o[2] = (bf16_t)v.z; o[3] = (bf16_t)v.w;
        ((bf16x4*)dst)[i] = o;
    }
}

// ---------------- fold per-by row-sum partials ----------------
__global__ __launch_bounds__(256) void k_foldrs(const float* __restrict__ rsPart,
                                                float* __restrict__ rsums) {
    const int r = blockIdx.x * 256 + threadIdx.x;
    float s = 0.f;
#pragma unroll
    for (int b = 0; b < 8; ++b) s += rsPart[b * 5120 + r];
    rsums[r] = s;
}

// ---------------- split-K reduce + final epilogue (scrambled partial layout) ------
__global__ __launch_bounds__(256) void k_reduce4(const bf16_t* __restrict__ part,
                                                 const float* __restrict__ rsums,
                                                 const float* __restrict__ pa,
                                                 float* __restrict__ out) {
    const int idx = blockIdx.x * 256 + threadIdx.x;  // [0, 524288)
    const int region = idx >> 13;                    // 64 regions (bx*4+by)
    const int widx = idx & 8191;
    const int wv = widx >> 10;
    const int chunk = (widx >> 6) & 15;
    const int ln = widx & 63;
    const int bx = region >> 2, by = region & 3;
    const int wm = wv >> 2, wn = wv & 3;
    const int fg = chunk >> 1, gp = chunk & 1;
    const int er = (ln >> 4) << 2, ec = ln & 15;
    const long off = (long)idx * 8;

    float sum[8] = {};
#pragma unroll
    for (int s = 0; s < 4; ++s) {
        bf16x8 v = *(const bf16x8*)(part + (long)s * 4194304 + off);
#pragma unroll
        for (int j = 0; j < 8; ++j) sum[j] += (float)v[j];
    }
    const int r0 = bx * 256 + wm * 128 + fg * 16 + er;
    const int c0 = by * 256 + wn * 64 + gp * 32 + ec;
    const float a = pa[0];
#pragma unroll
    for (int q = 0; q < 4; ++q) {
        const float ra = a * rsums[r0 + q];
#pragma unroll
        for (int gh = 0; gh < 2; ++gh) {
            const int c = c0 + gh * 16;
            out[(long)(r0 + q) * 1024 + c] = sum[gh * 4 + q] - ra - rsums[4096 + c];
        }
    }
}

// ================= GEMM2: ring-4 deep-pipelined 256x256, KB32 operands ==========
// R15 change: NO sched_barrier walls inside the phase -- compiler free to
// interleave ds_reads / gload issues / MFMAs (fine-grained lgkmcnt, m97 evidence).
__global__ __launch_bounds__(512, 2) void gemm2_8p(
    const bf16_t* __restrict__ A2s, const bf16_t* __restrict__ B2s,
    bf16_t* __restrict__ O1, long zstride) {
    __shared__ char lds[131072];
    const int tid = threadIdx.x;
    const int wave = tid >> 6, lane = tid & 63;
    const int wm = wave >> 2, wn = wave & 3;

    const int gx = gridDim.x, gy = gridDim.y;
    const int o = blockIdx.x + gx * (blockIdx.y + gy * blockIdx.z);
    const int cpx = (gx * gy * (int)gridDim.z) >> 3;
    const int v = (o & 7) * cpx + (o >> 3);
    const int bx = v % gx;
    const int rem = v / gx;
    const int by = rem % gy;
    const int bz = rem / gy;

    const long bm = (long)bx * 256, bn = (long)by * 256;
    const int kb32_0 = bz * 32;
    const char* Ab = (const char*)A2s;
    const char* Bb = (const char*)B2s;

    const int swzcb = ((lane >> 4) << 4) ^ (((lane >> 3) & 1) << 5);
    const int base_a = (wm * 128 + (lane & 15)) * 64 + swzcb;
    const int base_b = (wn * 64 + (lane & 15)) * 64 + swzcb;

    f32x4 acc[8][4] = {};

    auto STAGEC = [&](const char* gbase, int ldsoff) {
#pragma unroll
        for (int j = 0; j < 2; ++j) {
            const int oo = (j * 512 + tid) << 4;
            const int cb = (oo & 63) ^ (((oo >> 9) & 1) << 5);
            gload_lds16(gbase + (oo & ~63) + cb, lds + ldsoff + (oo & ~1023));
        }
    };

#define VM8 asm volatile("s_waitcnt vmcnt(8)" ::: "memory")
#define VM4 asm volatile("s_waitcnt vmcnt(4)" ::: "memory")
#define VM0 asm volatile("s_waitcnt vmcnt(0)" ::: "memory")

    auto PFETCH = [&](int pf) {
        const long kb = kb32_0 + pf;
        const int ps = pf & 3;
        STAGEC(Ab + (kb * 4096 + bm) * 64, ps * 16384);
        STAGEC(Bb + (kb * 1024 + bn) * 64, 65536 + ps * 16384);
    };

#define PHASE2(p, WAITSTMT, DOPF)                                               \
    do {                                                                        \
        WAITSTMT;                                                               \
        __builtin_amdgcn_s_barrier();                                           \
        __builtin_amdgcn_s_setprio(1);                                          \
        const int slot = (p) & 3;                                               \
        const char* sA = lds + slot * 16384;                                    \
        const char* sB = lds + 65536 + slot * 16384;                            \
        bf16x8 af[8];                                                           \
        bf16x8 bfr[4];                                                          \
        _Pragma("unroll") for (int f = 0; f < 8; ++f)                           \
            af[f] = *(const bf16x8*)(sA + base_a + f * 1024);                   \
        _Pragma("unroll") for (int g = 0; g < 4; ++g)                           \
            bfr[g] = *(const bf16x8*)(sB + base_b + g * 1024);                  \
        if (DOPF) PFETCH((p) + 3);                                              \
        _Pragma("unroll") for (int f = 0; f < 8; ++f)                           \
            _Pragma("unroll") for (int g = 0; g < 4; ++g)                       \
                acc[f][g] = __builtin_amdgcn_mfma_f32_16x16x32_bf16(            \
                    af[f], bfr[g], acc[f][g], 0, 0, 0);                         \
        __builtin_amdgcn_s_setprio(0);                                          \
    } while (0)

    const int NP = 32;
    PFETCH(0);
    PFETCH(1);
    PFETCH(2);

    for (int p = 0; p < NP - 3; ++p) PHASE2(p, VM8, 1);
    PHASE2(NP - 3, VM8, 0);
    PHASE2(NP - 2, VM4, 0);
    PHASE2(NP - 1, VM0, 0);

#undef PHASE2
#undef VM8
#undef VM4
#undef VM0

    // scrambled-coalesced partial write
    bf16_t* Op = O1 + (long)bz * zstride + (long)(bx * 4 + by) * 65536 +
                 wave * 8192 + lane * 8;
#pragma unroll
    for (int fg = 0; fg < 8; ++fg)
#pragma unroll
        for (int gp = 0; gp < 2; ++gp) {
            bf16x8 w;
#pragma unroll
            for (int gh = 0; gh < 2; ++gh)
#pragma unroll
                for (int q = 0; q < 4; ++q)
                    w[gh * 4 + q] = (bf16_t)acc[fg][gp * 2 + gh][q];
            *(bf16x8*)(Op + (fg * 2 + gp) * 512) = w;
        }
}

// ================= GEMM1: ring-4 160x256, grid 32x8, KB32 epilogue ===============
// R15 change: same wall removal in the phase body.
__global__ __launch_bounds__(512, 2) void gemm1_160(
    const bf16_t* __restrict__ A, const bf16_t* __restrict__ B,
    bf16_t* __restrict__ A2s, bf16_t* __restrict__ B2s,
    float* __restrict__ rsPart,
    const float* __restrict__ pa, const float* __restrict__ pb,
    const float* __restrict__ pt) {
    __shared__ char lds[106496];
    const int tid = threadIdx.x;
    const int wave = tid >> 6, lane = tid & 63;
    const int wm = wave >> 2, wn = wave & 3;
    const int NT = 16;

    const int gx = gridDim.x, gy = gridDim.y;
    const int o = blockIdx.x + gx * blockIdx.y;
    const int cpx = (gx * gy) >> 3;
    const int v = (o & 7) * cpx + (o >> 3);
    const int bx = v % gx;
    const int by = v / gx;

    const long bm = (long)bx * 160, bn = (long)by * 256;
    const char* Ab = (const char*)A + bm * 2048;
    const char* Bb = (const char*)B + bn * 2048;

    const int swzcb = ((lane >> 4) << 4) ^ (((lane >> 3) & 1) << 5);
    const int base_a = (wm * 80 + (lane & 15)) * 64 + swzcb;
    const int base_b = (wn * 64 + (lane & 15)) * 64 + swzcb;

    f32x4 acc[5][4] = {};

    auto STAGE_A = [&](int kbyte, int ldsoff) {
        {
            const int oo = tid << 4;
            const int r = oo >> 6;
            const int cb = (oo & 63) ^ (((oo >> 9) & 1) << 5);
            gload_lds16(Ab + (long)r * 2048 + kbyte + cb, lds + ldsoff + (oo & ~1023));
        }
        {
            const int oo = 8192 + (tid << 2);
            const int r = oo >> 6;
            const int cb = (oo & 63) ^ (((oo >> 9) & 1) << 5);
            gload_lds4(Ab + (long)r * 2048 + kbyte + cb, lds + ldsoff + 8192 + wave * 256);
        }
    };
    auto STAGE_B = [&](int kbyte, int ldsoff) {
#pragma unroll
        for (int j = 0; j < 2; ++j) {
            const int oo = (j * 512 + tid) << 4;
            const int r = oo >> 6;
            const int cb = (oo & 63) ^ (((oo >> 9) & 1) << 5);
            gload_lds16(Bb + (long)r * 2048 + kbyte + cb, lds + ldsoff + (oo & ~1023));
        }
    };

#define VM8 asm volatile("s_waitcnt vmcnt(8)" ::: "memory")
#define VM4 asm volatile("s_waitcnt vmcnt(4)" ::: "memory")
#define VM0 asm volatile("s_waitcnt vmcnt(0)" ::: "memory")

    auto PFETCH = [&](int pf) {
        const int kbyte = pf * 64;
        const int ps = pf & 3;
        STAGE_A(kbyte, ps * 10240);
        STAGE_B(kbyte, 40960 + ps * 16384);
    };

#define PHASE1(p, WAITSTMT, DOPF)                                               \
    do {                                                                        \
        WAITSTMT;                                                               \
        __builtin_amdgcn_s_barrier();                                           \
        __builtin_amdgcn_s_setprio(1);                                          \
        const int slot = (p) & 3;                                               \
        const char* sA = lds + slot * 10240;                                    \
        const char* sB = lds + 40960 + slot * 16384;                            \
        bf16x8 af[5];                                                           \
        bf16x8 bfr[4];                                                          \
        _Pragma("unroll") for (int f = 0; f < 5; ++f)                           \
            af[f] = *(const bf16x8*)(sA + base_a + f * 1024);                   \
        _Pragma("unroll") for (int g = 0; g < 4; ++g)                           \
            bfr[g] = *(const bf16x8*)(sB + base_b + g * 1024);                  \
        if (DOPF) PFETCH((p) + 3);                                              \
        _Pragma("unroll") for (int f = 0; f < 5; ++f)                           \
            _Pragma("unroll") for (int g = 0; g < 4; ++g)                       \
                acc[f][g] = __builtin_amdgcn_mfma_f32_16x16x32_bf16(            \
                    bfr[g], af[f], acc[f][g], 0, 0, 0);                         \
        __builtin_amdgcn_s_setprio(0);                                          \
    } while (0)

    const int NP = NT * 2;
    PFETCH(0);
    PFETCH(1);
    PFETCH(2);

    for (int p = 0; p < NP - 3; ++p) PHASE1(p, VM8, 1);
    PHASE1(NP - 3, VM8, 0);
    PHASE1(NP - 2, VM4, 0);
    PHASE1(NP - 1, VM0, 0);

#undef PHASE1
#undef VM8
#undef VM4
#undef VM0

    // Epilogue: direct KB32 stores. col f = bn + wn*64 + (g>>1)*32 + (g&1)*16+ln4+q
    const float va = pa[0], vb = pb[0], vt = pt[0];
    const int lm = lane & 15;
    const int ln4 = (lane >> 4) << 2;
    const int kbbase = (int)(bn >> 5) + wn * 2;
    float rs[5];
#pragma unroll
    for (int f = 0; f < 5; ++f) rs[f] = 0.f;

#pragma unroll
    for (int mf = 0; mf < 5; ++mf) {
        const long grow = bm + wm * 80 + mf * 16 + lm;
        const bool isXf = (grow < 4096);
        const long rowidx = isXf ? grow : (grow - 4096);
        const long rowsz = isXf ? 4096 : 1024;
        bf16_t* base = isXf ? A2s : B2s;
#pragma unroll
        for (int g = 0; g < 4; ++g) {
            bf16x4 w0, w1;
            float rsl = 0.f;
#pragma unroll
            for (int q = 0; q < 4; ++q) {
                const float vv = acc[mf][g][q];
                const float s = sigmoidf_(vv);
                const float prod = vv * s;
                w0[q] = (bf16_t)(isXf ? prod : (vt * prod + va * s));
                w1[q] = (bf16_t)(isXf ? s : (vb * prod));
                rsl += isXf ? prod : vb * prod;
            }
            rs[mf] += rsl;
            const long kb = kbbase + (g >> 1);
            const int c0 = (g & 1) * 16 + ln4;
            *(bf16x4*)(base + (kb * rowsz + rowidx) * 32 + c0) = w0;
            *(bf16x4*)(base + ((kb + 64) * rowsz + rowidx) * 32 + c0) = w1;
        }
    }

    // rowsums
    __syncthreads();
    float* lds_f = (float*)lds;
#pragma unroll
    for (int f = 0; f < 5; ++f) {
        float t = rs[f];
        t += __shfl_xor(t, 16);
        t += __shfl_xor(t, 32);
        if ((lane >> 4) == 0) lds_f[wn * 160 + wm * 80 + f * 16 + lm] = t;
    }
    __syncthreads();
    if (tid < 160) {
        const float s = lds_f[tid] + lds_f[160 + tid] + lds_f[320 + tid] + lds_f[480 + tid];
        rsPart[(long)by * 5120 + bm + tid] = s;
    }
}

extern "C" void kernel_launch(void* const* d_in, const int* in_sizes, int n_in,
                              void* d_out, int out_size, void* d_ws, size_t ws_size,
                              hipStream_t stream) {
    const float* x = (const float*)d_in[0];       // [4096,1024]
    const float* feats = (const float*)d_in[1];   // [2048,1024]
    const float* protos = (const float*)d_in[2];  // [1024,1024]
    const float* pa = (const float*)d_in[3];
    const float* pb = (const float*)d_in[4];
    const float* pt = (const float*)d_in[5];
    float* out = (float*)d_out;                   // [4096,1024]

    constexpr long Bsz = 4096, D = 1024, F = 2048, P = 1024;

    bf16_t* XP = (bf16_t*)d_ws;                   // [5120 x 1024] = [x ; protos]
    bf16_t* F16 = XP + (Bsz + P) * D;             // [2048 x 1024]
    bf16_t* A2s = F16 + F * D;                    // KB32: [128][4096][32], 32 MB
    bf16_t* B2s = A2s + Bsz * 2 * F;              // KB32: [128][1024][32], 8 MB
    float* rsums = (float*)(B2s + P * 2 * F);     // [5120] f32 (folded)
    bf16_t* part = (bf16_t*)(rsums + Bsz + P);    // 4 x [4096*1024] bf16 (scrambled)
    float* rsPart = (float*)(part + 4L * Bsz * P);  // [8][5120] f32 slabs

    k_convert3<<<2048, 256, 0, stream>>>(x, protos, feats, XP);

    // fused GEMM1: [x;protos] @ feats^T  [5120 x 2048], K=1024, 256 blocks
    gemm1_160<<<dim3(32, 8), 512, 0, stream>>>(XP, F16, A2s, B2s, rsPart, pa, pb, pt);

    // fold 8 per-by row-sum slabs -> rsums[5120]
    k_foldrs<<<20, 256, 0, stream>>>(rsPart, rsums);

    // GEMM2 split-K=4 over kb slices (scrambled partial layout)
    gemm2_8p<<<dim3(Bsz / 256, P / 256, 4), 512, 0, stream>>>(
        A2s, B2s, part, (long)Bsz * P);

    k_reduce4<<<2048, 256, 0, stream>>>(part, rsums, pa, out);
}

// Round 16
// 87.306 us; speedup vs baseline: 1.1383x; 1.0151x over previous
//
#include <hip/hip_runtime.h>
#include <hip/hip_bf16.h>

typedef __bf16 bf16_t;
typedef bf16_t bf16x4 __attribute__((ext_vector_type(4)));
typedef bf16_t bf16x8 __attribute__((ext_vector_type(8)));
typedef float f32x4 __attribute__((ext_vector_type(4)));

#define AS1 __attribute__((address_space(1)))
#define AS3 __attribute__((address_space(3)))

__device__ __forceinline__ void gload_lds16(const void* g, void* l) {
    __builtin_amdgcn_global_load_lds((const AS1 void*)g, (AS3 void*)l, 16, 0, 0);
}
__device__ __forceinline__ void gload_lds4(const void* g, void* l) {
    __builtin_amdgcn_global_load_lds((const AS1 void*)g, (AS3 void*)l, 4, 0, 0);
}

__device__ __forceinline__ float sigmoidf_(float v) {
    return 1.0f / (1.0f + __expf(-v));
}

// ---------------- fused f32 -> bf16 convert, KB32 blocked output ----------------
// XPs[kb][5120][32] <- [x ; protos] cols kb*32..kb*32+31;  F16s[kb][2048][32] <- feats.
__global__ __launch_bounds__(256) void k_convert3(const float* __restrict__ x,
                                                  const float* __restrict__ pr,
                                                  const float* __restrict__ ft,
                                                  bf16_t* __restrict__ XPs,
                                                  bf16_t* __restrict__ F16s) {
    const int n4 = 7168 * 256;
    int i = blockIdx.x * 256 + threadIdx.x;
    const int stride = gridDim.x * 256;
    for (; i < n4; i += stride) {
        float4 v;
        long r;
        int c4;
        bf16_t* dst;
        long R;
        if (i < 1048576) {
            v = ((const float4*)x)[i];
            r = i >> 8; c4 = i & 255; dst = XPs; R = 5120;
        } else if (i < 1310720) {
            const int j = i - 1048576;
            v = ((const float4*)pr)[j];
            r = 4096 + (j >> 8); c4 = j & 255; dst = XPs; R = 5120;
        } else {
            const int j = i - 1310720;
            v = ((const float4*)ft)[j];
            r = j >> 8; c4 = j & 255; dst = F16s; R = 2048;
        }
        const int col = c4 << 2;
        const int kb = col >> 5;
        const int cw = col & 31;
        bf16x4 o;
        o[0] = (bf16_t)v.x; o[1] = (bf16_t)v.y; o[2] = (bf16_t)v.z; o[3] = (bf16_t)v.w;
        *(bf16x4*)(dst + ((long)kb * R + r) * 32 + cw) = o;
    }
}

// ---------------- fold per-by row-sum partials ----------------
__global__ __launch_bounds__(256) void k_foldrs(const float* __restrict__ rsPart,
                                                float* __restrict__ rsums) {
    const int r = blockIdx.x * 256 + threadIdx.x;
    float s = 0.f;
#pragma unroll
    for (int b = 0; b < 8; ++b) s += rsPart[b * 5120 + r];
    rsums[r] = s;
}

// ---------------- split-K reduce + final epilogue (scrambled partial layout) ------
__global__ __launch_bounds__(256) void k_reduce4(const bf16_t* __restrict__ part,
                                                 const float* __restrict__ rsums,
                                                 const float* __restrict__ pa,
                                                 float* __restrict__ out) {
    const int idx = blockIdx.x * 256 + threadIdx.x;  // [0, 524288)
    const int region = idx >> 13;                    // 64 regions (bx*4+by)
    const int widx = idx & 8191;
    const int wv = widx >> 10;
    const int chunk = (widx >> 6) & 15;
    const int ln = widx & 63;
    const int bx = region >> 2, by = region & 3;
    const int wm = wv >> 2, wn = wv & 3;
    const int fg = chunk >> 1, gp = chunk & 1;
    const int er = (ln >> 4) << 2, ec = ln & 15;
    const long off = (long)idx * 8;

    float sum[8] = {};
#pragma unroll
    for (int s = 0; s < 4; ++s) {
        bf16x8 v = *(const bf16x8*)(part + (long)s * 4194304 + off);
#pragma unroll
        for (int j = 0; j < 8; ++j) sum[j] += (float)v[j];
    }
    const int r0 = bx * 256 + wm * 128 + fg * 16 + er;
    const int c0 = by * 256 + wn * 64 + gp * 32 + ec;
    const float a = pa[0];
#pragma unroll
    for (int q = 0; q < 4; ++q) {
        const float ra = a * rsums[r0 + q];
#pragma unroll
        for (int gh = 0; gh < 2; ++gh) {
            const int c = c0 + gh * 16;
            out[(long)(r0 + q) * 1024 + c] = sum[gh * 4 + q] - ra - rsums[4096 + c];
        }
    }
}

// ================= GEMM2: ring-4 deep-pipelined 256x256, KB32 operands ==========
__global__ __launch_bounds__(512, 2) void gemm2_8p(
    const bf16_t* __restrict__ A2s, const bf16_t* __restrict__ B2s,
    bf16_t* __restrict__ O1, long zstride) {
    __shared__ char lds[131072];
    const int tid = threadIdx.x;
    const int wave = tid >> 6, lane = tid & 63;
    const int wm = wave >> 2, wn = wave & 3;

    const int gx = gridDim.x, gy = gridDim.y;
    const int o = blockIdx.x + gx * (blockIdx.y + gy * blockIdx.z);
    const int cpx = (gx * gy * (int)gridDim.z) >> 3;
    const int v = (o & 7) * cpx + (o >> 3);
    const int bx = v % gx;
    const int rem = v / gx;
    const int by = rem % gy;
    const int bz = rem / gy;

    const long bm = (long)bx * 256, bn = (long)by * 256;
    const int kb32_0 = bz * 32;
    const char* Ab = (const char*)A2s;
    const char* Bb = (const char*)B2s;

    const int swzcb = ((lane >> 4) << 4) ^ (((lane >> 3) & 1) << 5);
    const int base_a = (wm * 128 + (lane & 15)) * 64 + swzcb;
    const int base_b = (wn * 64 + (lane & 15)) * 64 + swzcb;

    f32x4 acc[8][4] = {};

    auto STAGEC = [&](const char* gbase, int ldsoff) {
#pragma unroll
        for (int j = 0; j < 2; ++j) {
            const int oo = (j * 512 + tid) << 4;
            const int cb = (oo & 63) ^ (((oo >> 9) & 1) << 5);
            gload_lds16(gbase + (oo & ~63) + cb, lds + ldsoff + (oo & ~1023));
        }
    };

#define VM8 asm volatile("s_waitcnt vmcnt(8)" ::: "memory")
#define VM4 asm volatile("s_waitcnt vmcnt(4)" ::: "memory")
#define VM0 asm volatile("s_waitcnt vmcnt(0)" ::: "memory")

    auto PFETCH = [&](int pf) {
        const long kb = kb32_0 + pf;
        const int ps = pf & 3;
        STAGEC(Ab + (kb * 4096 + bm) * 64, ps * 16384);
        STAGEC(Bb + (kb * 1024 + bn) * 64, 65536 + ps * 16384);
    };

#define PHASE2(p, WAITSTMT, DOPF)                                               \
    do {                                                                        \
        WAITSTMT;                                                               \
        __builtin_amdgcn_s_barrier();                                           \
        __builtin_amdgcn_s_setprio(1);                                          \
        const int slot = (p) & 3;                                               \
        const char* sA = lds + slot * 16384;                                    \
        const char* sB = lds + 65536 + slot * 16384;                            \
        bf16x8 af[8];                                                           \
        bf16x8 bfr[4];                                                          \
        _Pragma("unroll") for (int f = 0; f < 8; ++f)                           \
            af[f] = *(const bf16x8*)(sA + base_a + f * 1024);                   \
        _Pragma("unroll") for (int g = 0; g < 4; ++g)                           \
            bfr[g] = *(const bf16x8*)(sB + base_b + g * 1024);                  \
        if (DOPF) PFETCH((p) + 3);                                              \
        _Pragma("unroll") for (int f = 0; f < 8; ++f)                           \
            _Pragma("unroll") for (int g = 0; g < 4; ++g)                       \
                acc[f][g] = __builtin_amdgcn_mfma_f32_16x16x32_bf16(            \
                    af[f], bfr[g], acc[f][g], 0, 0, 0);                         \
        __builtin_amdgcn_s_setprio(0);                                          \
    } while (0)

    const int NP = 32;
    PFETCH(0);
    PFETCH(1);
    PFETCH(2);

    for (int p = 0; p < NP - 3; ++p) PHASE2(p, VM8, 1);
    PHASE2(NP - 3, VM8, 0);
    PHASE2(NP - 2, VM4, 0);
    PHASE2(NP - 1, VM0, 0);

#undef PHASE2
#undef VM8
#undef VM4
#undef VM0

    // scrambled-coalesced partial write
    bf16_t* Op = O1 + (long)bz * zstride + (long)(bx * 4 + by) * 65536 +
                 wave * 8192 + lane * 8;
#pragma unroll
    for (int fg = 0; fg < 8; ++fg)
#pragma unroll
        for (int gp = 0; gp < 2; ++gp) {
            bf16x8 w;
#pragma unroll
            for (int gh = 0; gh < 2; ++gh)
#pragma unroll
                for (int q = 0; q < 4; ++q)
                    w[gh * 4 + q] = (bf16_t)acc[fg][gp * 2 + gh][q];
            *(bf16x8*)(Op + (fg * 2 + gp) * 512) = w;
        }
}

// ================= GEMM1: ring-4 160x256, KB32 inputs AND outputs ===============
// A-slice = XPs[kb][bm:bm+160][32] contiguous 10240B (16B + 4B loads, linear).
// B-slice = F16s[kb][bn:bn+256][32] contiguous 16KB. LDS image identical to all
// prior rounds ([row][64B] + swizzle involution) -> ds_read bases unchanged.
__global__ __launch_bounds__(512, 2) void gemm1_160(
    const bf16_t* __restrict__ XPs, const bf16_t* __restrict__ F16s,
    bf16_t* __restrict__ A2s, bf16_t* __restrict__ B2s,
    float* __restrict__ rsPart,
    const float* __restrict__ pa, const float* __restrict__ pb,
    const float* __restrict__ pt) {
    __shared__ char lds[106496];
    const int tid = threadIdx.x;
    const int wave = tid >> 6, lane = tid & 63;
    const int wm = wave >> 2, wn = wave & 3;

    const int gx = gridDim.x, gy = gridDim.y;
    const int o = blockIdx.x + gx * blockIdx.y;
    const int cpx = (gx * gy) >> 3;
    const int v = (o & 7) * cpx + (o >> 3);
    const int bx = v % gx;
    const int by = v / gx;

    const long bm = (long)bx * 160, bn = (long)by * 256;
    const char* Ab = (const char*)XPs;
    const char* Bb = (const char*)F16s;

    const int swzcb = ((lane >> 4) << 4) ^ (((lane >> 3) & 1) << 5);
    const int base_a = (wm * 80 + (lane & 15)) * 64 + swzcb;
    const int base_b = (wn * 64 + (lane & 15)) * 64 + swzcb;

    f32x4 acc[5][4] = {};

#define VM8 asm volatile("s_waitcnt vmcnt(8)" ::: "memory")
#define VM4 asm volatile("s_waitcnt vmcnt(4)" ::: "memory")
#define VM0 asm volatile("s_waitcnt vmcnt(0)" ::: "memory")

    auto PFETCH = [&](int pf) {  // pf = kb slice index 0..31
        const int ps = pf & 3;
        const char* Ag = Ab + ((long)pf * 5120 + bm) * 64;
        const char* Bg = Bb + ((long)pf * 2048 + bn) * 64;
        {
            const int oo = tid << 4;
            const int cb = (oo & 63) ^ (((oo >> 9) & 1) << 5);
            gload_lds16(Ag + (oo & ~63) + cb, lds + ps * 10240 + (oo & ~1023));
        }
        {
            const int oo = 8192 + (tid << 2);
            const int cb = (oo & 63) ^ (((oo >> 9) & 1) << 5);
            gload_lds4(Ag + (oo & ~63) + cb, lds + ps * 10240 + 8192 + wave * 256);
        }
#pragma unroll
        for (int j = 0; j < 2; ++j) {
            const int oo = (j * 512 + tid) << 4;
            const int cb = (oo & 63) ^ (((oo >> 9) & 1) << 5);
            gload_lds16(Bg + (oo & ~63) + cb, lds + 40960 + ps * 16384 + (oo & ~1023));
        }
    };

#define PHASE1(p, WAITSTMT, DOPF)                                               \
    do {                                                                        \
        WAITSTMT;                                                               \
        __builtin_amdgcn_s_barrier();                                           \
        __builtin_amdgcn_s_setprio(1);                                          \
        const int slot = (p) & 3;                                               \
        const char* sA = lds + slot * 10240;                                    \
        const char* sB = lds + 40960 + slot * 16384;                            \
        bf16x8 af[5];                                                           \
        bf16x8 bfr[4];                                                          \
        _Pragma("unroll") for (int f = 0; f < 5; ++f)                           \
            af[f] = *(const bf16x8*)(sA + base_a + f * 1024);                   \
        _Pragma("unroll") for (int g = 0; g < 4; ++g)                           \
            bfr[g] = *(const bf16x8*)(sB + base_b + g * 1024);                  \
        if (DOPF) PFETCH((p) + 3);                                              \
        _Pragma("unroll") for (int f = 0; f < 5; ++f)                           \
            _Pragma("unroll") for (int g = 0; g < 4; ++g)                       \
                acc[f][g] = __builtin_amdgcn_mfma_f32_16x16x32_bf16(            \
                    bfr[g], af[f], acc[f][g], 0, 0, 0);                         \
        __builtin_amdgcn_s_setprio(0);                                          \
    } while (0)

    const int NP = 32;
    PFETCH(0);
    PFETCH(1);
    PFETCH(2);

    for (int p = 0; p < NP - 3; ++p) PHASE1(p, VM8, 1);
    PHASE1(NP - 3, VM8, 0);
    PHASE1(NP - 2, VM4, 0);
    PHASE1(NP - 1, VM0, 0);

#undef PHASE1
#undef VM8
#undef VM4
#undef VM0

    // Epilogue: direct KB32 stores. col f = bn + wn*64 + (g>>1)*32 + (g&1)*16+ln4+q
    const float va = pa[0], vb = pb[0], vt = pt[0];
    const int lm = lane & 15;
    const int ln4 = (lane >> 4) << 2;
    const int kbbase = (int)(bn >> 5) + wn * 2;
    float rs[5];
#pragma unroll
    for (int f = 0; f < 5; ++f) rs[f] = 0.f;

#pragma unroll
    for (int mf = 0; mf < 5; ++mf) {
        const long grow = bm + wm * 80 + mf * 16 + lm;
        const bool isXf = (grow < 4096);
        const long rowidx = isXf ? grow : (grow - 4096);
        const long rowsz = isXf ? 4096 : 1024;
        bf16_t* base = isXf ? A2s : B2s;
#pragma unroll
        for (int g = 0; g < 4; ++g) {
            bf16x4 w0, w1;
            float rsl = 0.f;
#pragma unroll
            for (int q = 0; q < 4; ++q) {
                const float vv = acc[mf][g][q];
                const float s = sigmoidf_(vv);
                const float prod = vv * s;
                w0[q] = (bf16_t)(isXf ? prod : (vt * prod + va * s));
                w1[q] = (bf16_t)(isXf ? s : (vb * prod));
                rsl += isXf ? prod : vb * prod;
            }
            rs[mf] += rsl;
            const long kb = kbbase + (g >> 1);
            const int c0 = (g & 1) * 16 + ln4;
            *(bf16x4*)(base + (kb * rowsz + rowidx) * 32 + c0) = w0;
            *(bf16x4*)(base + ((kb + 64) * rowsz + rowidx) * 32 + c0) = w1;
        }
    }

    // rowsums
    __syncthreads();
    float* lds_f = (float*)lds;
#pragma unroll
    for (int f = 0; f < 5; ++f) {
        float t = rs[f];
        t += __shfl_xor(t, 16);
        t += __shfl_xor(t, 32);
        if ((lane >> 4) == 0) lds_f[wn * 160 + wm * 80 + f * 16 + lm] = t;
    }
    __syncthreads();
    if (tid < 160) {
        const float s = lds_f[tid] + lds_f[160 + tid] + lds_f[320 + tid] + lds_f[480 + tid];
        rsPart[(long)by * 5120 + bm + tid] = s;
    }
}

extern "C" void kernel_launch(void* const* d_in, const int* in_sizes, int n_in,
                              void* d_out, int out_size, void* d_ws, size_t ws_size,
                              hipStream_t stream) {
    const float* x = (const float*)d_in[0];       // [4096,1024]
    const float* feats = (const float*)d_in[1];   // [2048,1024]
    const float* protos = (const float*)d_in[2];  // [1024,1024]
    const float* pa = (const float*)d_in[3];
    const float* pb = (const float*)d_in[4];
    const float* pt = (const float*)d_in[5];
    float* out = (float*)d_out;                   // [4096,1024]

    constexpr long Bsz = 4096, D = 1024, F = 2048, P = 1024;

    bf16_t* XPs = (bf16_t*)d_ws;                  // KB32: [32][5120][32], 10 MB
    bf16_t* F16s = XPs + (Bsz + P) * D;           // KB32: [32][2048][32], 4 MB
    bf16_t* A2s = F16s + F * D;                   // KB32: [128][4096][32], 32 MB
    bf16_t* B2s = A2s + Bsz * 2 * F;              // KB32: [128][1024][32], 8 MB
    float* rsums = (float*)(B2s + P * 2 * F);     // [5120] f32 (folded)
    bf16_t* part = (bf16_t*)(rsums + Bsz + P);    // 4 x [4096*1024] bf16 (scrambled)
    float* rsPart = (float*)(part + 4L * Bsz * P);  // [8][5120] f32 slabs

    k_convert3<<<2048, 256, 0, stream>>>(x, protos, feats, XPs, F16s);

    // fused GEMM1: [x;protos] @ feats^T  [5120 x 2048], K=1024, 256 blocks
    gemm1_160<<<dim3(32, 8), 512, 0, stream>>>(XPs, F16s, A2s, B2s, rsPart, pa, pb, pt);

    // fold 8 per-by row-sum slabs -> rsums[5120]
    k_foldrs<<<20, 256, 0, stream>>>(rsPart, rsums);

    // GEMM2 split-K=4 over kb slices (scrambled partial layout)
    gemm2_8p<<<dim3(Bsz / 256, P / 256, 4), 512, 0, stream>>>(
        A2s, B2s, part, (long)Bsz * P);

    k_reduce4<<<2048, 256, 0, stream>>>(part, rsums, pa, out);
}